// Round 1
// baseline (1388.329 us; speedup 1.0000x reference)
//
#include <hip/hip_runtime.h>

constexpr int kB  = 32;
constexpr int kNQ = 256;
constexpr int kNT = 512;
constexpr float kInf = 1e30f;
constexpr int kQT = 16;

__global__ __launch_bounds__(256)
void cost_kernel(const float* __restrict__ trans,
                 const float* __restrict__ qpos,
                 const float* __restrict__ rot,
                 const float* __restrict__ pose,
                 float* __restrict__ cost)
{
    __shared__ float sPose[kNT * 23];
    __shared__ float sQ[kQT * 23];
    __shared__ float sValid[kNT];

    const int b     = blockIdx.x;
    const int qBase = blockIdx.y * kQT;
    const int tid   = threadIdx.x;

    const float* pb = pose + (size_t)b * kNT * 23;
    for (int idx = tid; idx < kNT * 23; idx += 256) sPose[idx] = pb[idx];

    for (int idx = tid; idx < kQT * 23; idx += 256) {
        const int q = idx / 23, d = idx % 23;
        const int gq = qBase + q;
        float val;
        if (d < 3)       val = trans[((size_t)b * kNQ + gq) * 3  + d];
        else if (d < 19) val = qpos [((size_t)b * kNQ + gq) * 16 + (d - 3)];
        else             val = rot  [((size_t)b * kNQ + gq) * 4  + (d - 19)];
        sQ[idx] = val;
    }
    __syncthreads();

    for (int t = tid; t < kNT; t += 256) {
        float s = 0.f;
        #pragma unroll
        for (int d = 0; d < 23; ++d) s += fabsf(sPose[t * 23 + d]);
        sValid[t] = (s > 0.f) ? 1.f : 0.f;
    }
    __syncthreads();

    float* cb = cost + ((size_t)b * kNQ + qBase) * kNT;
    for (int q = 0; q < kQT; ++q) {
        const float* Q = sQ + q * 23;
        for (int t = tid; t < kNT; t += 256) {
            const float* T = sPose + t * 23;
            float a = fabsf(Q[0] - T[0]);
            a += fabsf(Q[1] - T[1]);
            a += fabsf(Q[2] - T[2]);
            float bsum = 0.f;
            #pragma unroll
            for (int d = 0; d < 16; ++d) bsum += fabsf(Q[3 + d] - T[3 + d]);
            float dot = Q[19] * T[19] + Q[20] * T[20] + Q[21] * T[21] + Q[22] * T[22];
            float c = (a + bsum) + (1.0f - fabsf(dot));
            cb[(size_t)q * kNT + t] = (sValid[t] > 0.f) ? c : kInf;
        }
    }
}

__global__ __launch_bounds__(512)
void hungarian_kernel(const float* __restrict__ cost,
                      float* __restrict__ outInds,
                      float* __restrict__ outMask)
{
    __shared__ float u[kNQ];
    __shared__ float v[kNT];
    __shared__ float spc[kNT];
    __shared__ int   col4row[kNQ];
    __shared__ int   row4col[kNT];
    __shared__ int   path[kNT];
    __shared__ unsigned char SR[kNQ];
    __shared__ unsigned char SC[kNT];
    __shared__ int   bcast_i;
    __shared__ int   bcast_sink;
    __shared__ float bcast_minVal;
    __shared__ float warpVal[8];
    __shared__ int   warpIdx[8];

    const int b   = blockIdx.x;
    const int tid = threadIdx.x;
    const float* C = cost + (size_t)b * kNQ * kNT;

    if (tid < kNQ) { u[tid] = 0.f; col4row[tid] = -1; }
    v[tid] = 0.f; row4col[tid] = -1;
    __syncthreads();

    for (int cur = 0; cur < kNQ; ++cur) {
        if (tid < kNQ) SR[tid] = 0;
        spc[tid] = kInf; path[tid] = -1; SC[tid] = 0;
        if (tid == 0) { bcast_i = cur; bcast_minVal = 0.f; bcast_sink = -1; }
        __syncthreads();

        int   i      = cur;
        float minVal = 0.f;
        int   sink   = -1;
        int   guard  = 0;

        while (sink < 0 && guard <= kNT + 1) {
            ++guard;
            if (tid == 0) SR[i] = 1;
            const float ui = u[i];
            if (!SC[tid]) {
                const float r = ((minVal + C[(size_t)i * kNT + tid]) - ui) - v[tid];
                if (r < spc[tid]) { spc[tid] = r; path[tid] = i; }
            }
            __syncthreads();

            float val = SC[tid] ? kInf : spc[tid];
            int   idx = tid;
            #pragma unroll
            for (int off = 32; off > 0; off >>= 1) {
                const float oval = __shfl_down(val, off, 64);
                const int   oidx = __shfl_down(idx, off, 64);
                if (oval < val || (oval == val && oidx < idx)) { val = oval; idx = oidx; }
            }
            if ((tid & 63) == 0) { warpVal[tid >> 6] = val; warpIdx[tid >> 6] = idx; }
            __syncthreads();

            if (tid == 0) {
                float bv = warpVal[0];
                int   bi = warpIdx[0];
                #pragma unroll
                for (int w = 1; w < 8; ++w) {
                    if (warpVal[w] < bv || (warpVal[w] == bv && warpIdx[w] < bi)) {
                        bv = warpVal[w]; bi = warpIdx[w];
                    }
                }
                bcast_minVal = bv;
                SC[bi] = 1;
                const int r4 = row4col[bi];
                if (r4 < 0) bcast_sink = bi;
                else        bcast_i    = r4;
            }
            __syncthreads();
            minVal = bcast_minVal;
            sink   = bcast_sink;
            i      = bcast_i;
            __syncthreads();
        }

        if (tid < kNQ && SR[tid]) {
            float du;
            if (tid == cur) du = minVal;
            else {
                int cj = col4row[tid];
                cj = cj < 0 ? 0 : (cj >= kNT ? kNT - 1 : cj);
                du = minVal - spc[cj];
            }
            u[tid] += du;
        }
        if (SC[tid]) v[tid] -= (minVal - spc[tid]);
        __syncthreads();

        if (tid == 0 && sink >= 0) {
            int j = sink;
            while (true) {
                const int pi = path[j];
                row4col[j] = pi;
                const int nj = col4row[pi];
                col4row[pi] = j;
                if (pi == cur) break;
                j = nj;
            }
        }
        __syncthreads();
    }

    if (tid < kNQ) {
        outInds[(size_t)b * kNQ + tid] = (float)col4row[tid];
        outMask[(size_t)b * kNQ + tid] = 1.0f;
    }
}

extern "C" void kernel_launch(void* const* d_in, const int* in_sizes, int n_in,
                              void* d_out, int out_size, void* d_ws, size_t ws_size,
                              hipStream_t stream) {
    const float* trans = (const float*)d_in[0];
    const float* qpos  = (const float*)d_in[1];
    const float* rot   = (const float*)d_in[2];
    const float* pose  = (const float*)d_in[3];

    float* out  = (float*)d_out;
    float* cost = out;
    float* inds = out + (size_t)kB * kNQ * kNT;
    float* mask = inds + (size_t)kB * kNQ;

    dim3 g1(kB, kNQ / kQT);
    cost_kernel<<<g1, 256, 0, stream>>>(trans, qpos, rot, pose, cost);
    hungarian_kernel<<<kB, kNT, 0, stream>>>(cost, inds, mask);
}

// Round 2
// 687.102 us; speedup vs baseline: 2.0206x; 2.0206x over previous
//
#include <hip/hip_runtime.h>

constexpr int kB  = 32;
constexpr int kNQ = 256;   // rows n
constexpr int kNT = 512;   // cols m
constexpr float kInf = 1e30f;
constexpr int kQT = 16;

// ---------------------------------------------------------------------------
// Kernel 1: final_cost [B, NQ, NT]  (unchanged from R1 — correct, ~tens of µs)
// ---------------------------------------------------------------------------
__global__ __launch_bounds__(256)
void cost_kernel(const float* __restrict__ trans,
                 const float* __restrict__ qpos,
                 const float* __restrict__ rot,
                 const float* __restrict__ pose,
                 float* __restrict__ cost)
{
    __shared__ float sPose[kNT * 23];
    __shared__ float sQ[kQT * 23];
    __shared__ float sValid[kNT];

    const int b     = blockIdx.x;
    const int qBase = blockIdx.y * kQT;
    const int tid   = threadIdx.x;

    const float* pb = pose + (size_t)b * kNT * 23;
    for (int idx = tid; idx < kNT * 23; idx += 256) sPose[idx] = pb[idx];

    for (int idx = tid; idx < kQT * 23; idx += 256) {
        const int q = idx / 23, d = idx % 23;
        const int gq = qBase + q;
        float val;
        if (d < 3)       val = trans[((size_t)b * kNQ + gq) * 3  + d];
        else if (d < 19) val = qpos [((size_t)b * kNQ + gq) * 16 + (d - 3)];
        else             val = rot  [((size_t)b * kNQ + gq) * 4  + (d - 19)];
        sQ[idx] = val;
    }
    __syncthreads();

    for (int t = tid; t < kNT; t += 256) {
        float s = 0.f;
        #pragma unroll
        for (int d = 0; d < 23; ++d) s += fabsf(sPose[t * 23 + d]);
        sValid[t] = (s > 0.f) ? 1.f : 0.f;
    }
    __syncthreads();

    float* cb = cost + ((size_t)b * kNQ + qBase) * kNT;
    for (int q = 0; q < kQT; ++q) {
        const float* Q = sQ + q * 23;
        for (int t = tid; t < kNT; t += 256) {
            const float* T = sPose + t * 23;
            float a = fabsf(Q[0] - T[0]);
            a += fabsf(Q[1] - T[1]);
            a += fabsf(Q[2] - T[2]);
            float bsum = 0.f;
            #pragma unroll
            for (int d = 0; d < 16; ++d) bsum += fabsf(Q[3 + d] - T[3 + d]);
            float dot = Q[19] * T[19] + Q[20] * T[20] + Q[21] * T[21] + Q[22] * T[22];
            float c = (a + bsum) + (1.0f - fabsf(dot));
            cb[(size_t)q * kNT + t] = (sValid[t] > 0.f) ? c : kInf;
        }
    }
}

// ---------------------------------------------------------------------------
// Kernel 2: JV LSAP with row-reduction init + single-wave register-resident
// augmenting search. One block (256 thr) per batch.
//   Phase 1 (all 256 threads): u[i] = min_j C[i,j]; greedy-match argmin cols
//     (lowest row index wins via LDS atomicMin). Feasible duals + CS hold.
//   Phase 2 (wave 0 only, zero barriers): Dijkstra augmenting search for the
//     ~55 unmatched rows. Lane owns 8 contiguous cols; spc/path/v/SC in
//     registers; argmin = sortable-u64 shfl_xor butterfly (val, lowest idx).
// ---------------------------------------------------------------------------
__global__ __launch_bounds__(256)
void hungarian_kernel(const float* __restrict__ cost,
                      float* __restrict__ outInds,
                      float* __restrict__ outMask)
{
    __shared__ float u[kNQ];
    __shared__ int   col4row[kNQ];
    __shared__ int   row4col[kNT];
    __shared__ int   colBest[kNT];
    __shared__ int   pathL[kNT];
    __shared__ int   rowArg[kNQ];

    const int b   = blockIdx.x;
    const int tid = threadIdx.x;
    const float* __restrict__ C = cost + (size_t)b * kNQ * kNT;

    // ---- Phase 1: row minima + greedy matching (thread t == row t) ----
    {
        const float4* Crow = (const float4*)(C + (size_t)tid * kNT);
        float bm = kInf; int barg = 0;
        #pragma unroll 4
        for (int j4 = 0; j4 < kNT / 4; ++j4) {
            float4 cc = Crow[j4];
            const int jb = j4 * 4;
            if (cc.x < bm) { bm = cc.x; barg = jb + 0; }
            if (cc.y < bm) { bm = cc.y; barg = jb + 1; }
            if (cc.z < bm) { bm = cc.z; barg = jb + 2; }
            if (cc.w < bm) { bm = cc.w; barg = jb + 3; }
        }
        u[tid]      = bm;     // feasible: C - u - v >= 0 with v = 0
        rowArg[tid] = barg;
        col4row[tid] = -1;
    }
    row4col[tid] = -1;       row4col[tid + 256] = -1;
    colBest[tid] = 0x7fffffff; colBest[tid + 256] = 0x7fffffff;
    __syncthreads();
    atomicMin(&colBest[rowArg[tid]], tid);
    __syncthreads();
    {
        const int j = rowArg[tid];
        if (colBest[j] == tid) { col4row[tid] = j; row4col[j] = tid; }
    }
    __syncthreads();

    // ---- Phase 2: augmenting searches, wave 0 only (wave-synchronous) ----
    if (tid < 64) {
        const int lane = tid;
        float vR[8];
        #pragma unroll
        for (int c = 0; c < 8; ++c) vR[c] = 0.f;

        for (int cur = 0; cur < kNQ; ++cur) {
            if (col4row[cur] >= 0) continue;   // uniform branch

            float spcR[8]; int pathR[8];
            #pragma unroll
            for (int c = 0; c < 8; ++c) { spcR[c] = kInf; pathR[c] = -1; }
            unsigned scMask = 0;

            int   i      = cur;
            float minVal = 0.f;
            int   sink   = -1;

            for (int guard = 0; guard < kNT + 2 && sink < 0; ++guard) {
                const float ui = u[i];
                const float4* rp = (const float4*)(C + (size_t)i * kNT + lane * 8);
                const float4 p0 = rp[0], p1 = rp[1];
                const float cc[8] = {p0.x, p0.y, p0.z, p0.w, p1.x, p1.y, p1.z, p1.w};
                #pragma unroll
                for (int c = 0; c < 8; ++c) {
                    if (!((scMask >> c) & 1u)) {
                        const float r = ((minVal + cc[c]) - ui) - vR[c];
                        if (r < spcR[c]) { spcR[c] = r; pathR[c] = i; }
                    }
                }
                // local argmin (ascending col, strict < => lowest index on tie)
                float lv = kInf; int lidx = 0x7fffffff;
                #pragma unroll
                for (int c = 0; c < 8; ++c) {
                    const float valc = ((scMask >> c) & 1u) ? kInf : spcR[c];
                    if (valc < lv) { lv = valc; lidx = lane * 8 + c; }
                }
                // pack (value, index) into order-preserving u64; min = argmin w/ lowest-idx tie-break
                unsigned fb = __float_as_uint(lv);
                fb = (fb & 0x80000000u) ? ~fb : (fb | 0x80000000u);
                unsigned long long key =
                    ((unsigned long long)fb << 32) | (unsigned)lidx;
                #pragma unroll
                for (int off = 1; off < 64; off <<= 1) {
                    const unsigned long long ok = __shfl_xor(key, off, 64);
                    key = (ok < key) ? ok : key;
                }
                const int jstar = (int)(key & 0xffffffffull);
                unsigned mfb = (unsigned)(key >> 32);
                mfb = (mfb & 0x80000000u) ? (mfb & 0x7fffffffu) : ~mfb;
                minVal = __uint_as_float(mfb);

                if ((jstar >> 3) == lane) scMask |= 1u << (jstar & 7);
                const int rj = row4col[jstar];
                if (rj < 0) sink = jstar;
                else        i    = rj;
            }

            // ---- dual updates (register-local; col4row[row4col[j]] == j) ----
            if (lane == 0) u[cur] += minVal;
            #pragma unroll
            for (int c = 0; c < 8; ++c) {
                if ((scMask >> c) & 1u) {
                    const int j = lane * 8 + c;
                    const int r = row4col[j];
                    const float d = minVal - spcR[c];
                    if (r >= 0) u[r] += d;   // distinct rows across lanes (matching)
                    vR[c] -= d;
                    pathL[j] = pathR[c];
                }
            }
            __threadfence_block();

            // ---- augment along alternating path (lane 0) ----
            if (lane == 0 && sink >= 0) {
                int j = sink;
                while (true) {
                    const int pi = pathL[j];
                    row4col[j] = pi;
                    const int nj = col4row[pi];
                    col4row[pi] = j;
                    if (pi == cur) break;
                    j = nj;
                }
            }
            __threadfence_block();
        }
    }
    __syncthreads();

    outInds[(size_t)b * kNQ + tid] = (float)col4row[tid];
    outMask[(size_t)b * kNQ + tid] = 1.0f;
}

extern "C" void kernel_launch(void* const* d_in, const int* in_sizes, int n_in,
                              void* d_out, int out_size, void* d_ws, size_t ws_size,
                              hipStream_t stream) {
    const float* trans = (const float*)d_in[0];
    const float* qpos  = (const float*)d_in[1];
    const float* rot   = (const float*)d_in[2];
    const float* pose  = (const float*)d_in[3];

    float* out  = (float*)d_out;
    float* cost = out;
    float* inds = out + (size_t)kB * kNQ * kNT;
    float* mask = inds + (size_t)kB * kNQ;

    dim3 g1(kB, kNQ / kQT);
    cost_kernel<<<g1, 256, 0, stream>>>(trans, qpos, rot, pose, cost);
    hungarian_kernel<<<kB, 256, 0, stream>>>(cost, inds, mask);
}

// Round 5
// 543.007 us; speedup vs baseline: 2.5567x; 1.2654x over previous
//
#include <hip/hip_runtime.h>

constexpr int kB  = 32;
constexpr int kNQ = 256;   // rows n
constexpr int kNT = 512;   // cols m
constexpr float kInf = 1e30f;
constexpr int kQT = 16;

// ---------------------------------------------------------------------------
// Kernel 1: final_cost [B, NQ, NT]  (unchanged — proven)
// ---------------------------------------------------------------------------
__global__ __launch_bounds__(256)
void cost_kernel(const float* __restrict__ trans,
                 const float* __restrict__ qpos,
                 const float* __restrict__ rot,
                 const float* __restrict__ pose,
                 float* __restrict__ cost)
{
    __shared__ float sPose[kNT * 23];
    __shared__ float sQ[kQT * 23];
    __shared__ float sValid[kNT];

    const int b     = blockIdx.x;
    const int qBase = blockIdx.y * kQT;
    const int tid   = threadIdx.x;

    const float* pb = pose + (size_t)b * kNT * 23;
    for (int idx = tid; idx < kNT * 23; idx += 256) sPose[idx] = pb[idx];

    for (int idx = tid; idx < kQT * 23; idx += 256) {
        const int q = idx / 23, d = idx % 23;
        const int gq = qBase + q;
        float val;
        if (d < 3)       val = trans[((size_t)b * kNQ + gq) * 3  + d];
        else if (d < 19) val = qpos [((size_t)b * kNQ + gq) * 16 + (d - 3)];
        else             val = rot  [((size_t)b * kNQ + gq) * 4  + (d - 19)];
        sQ[idx] = val;
    }
    __syncthreads();

    for (int t = tid; t < kNT; t += 256) {
        float s = 0.f;
        #pragma unroll
        for (int d = 0; d < 23; ++d) s += fabsf(sPose[t * 23 + d]);
        sValid[t] = (s > 0.f) ? 1.f : 0.f;
    }
    __syncthreads();

    float* cb = cost + ((size_t)b * kNQ + qBase) * kNT;
    for (int q = 0; q < kQT; ++q) {
        const float* Q = sQ + q * 23;
        for (int t = tid; t < kNT; t += 256) {
            const float* T = sPose + t * 23;
            float a = fabsf(Q[0] - T[0]);
            a += fabsf(Q[1] - T[1]);
            a += fabsf(Q[2] - T[2]);
            float bsum = 0.f;
            #pragma unroll
            for (int d = 0; d < 16; ++d) bsum += fabsf(Q[3 + d] - T[3 + d]);
            float dot = Q[19] * T[19] + Q[20] * T[20] + Q[21] * T[21] + Q[22] * T[22];
            float c = (a + bsum) + (1.0f - fabsf(dot));
            cb[(size_t)q * kNT + t] = (sValid[t] > 0.f) ? c : kInf;
        }
    }
}

// Wave64 min-reduction via DPP (rocPRIM pattern). All inputs are non-negative
// float bit-patterns, so u32 order == f32 order. Result broadcast via lane 63.
__device__ __forceinline__ unsigned wave_min_u32(unsigned x) {
    unsigned t;
    t = (unsigned)__builtin_amdgcn_update_dpp((int)0xFFFFFFFF, (int)x, 0x111, 0xF, 0xF, false); x = t < x ? t : x; // row_shr:1
    t = (unsigned)__builtin_amdgcn_update_dpp((int)0xFFFFFFFF, (int)x, 0x112, 0xF, 0xF, false); x = t < x ? t : x; // row_shr:2
    t = (unsigned)__builtin_amdgcn_update_dpp((int)0xFFFFFFFF, (int)x, 0x114, 0xF, 0xF, false); x = t < x ? t : x; // row_shr:4
    t = (unsigned)__builtin_amdgcn_update_dpp((int)0xFFFFFFFF, (int)x, 0x118, 0xF, 0xF, false); x = t < x ? t : x; // row_shr:8
    t = (unsigned)__builtin_amdgcn_update_dpp((int)0xFFFFFFFF, (int)x, 0x142, 0xF, 0xF, false); x = t < x ? t : x; // row_bcast:15
    t = (unsigned)__builtin_amdgcn_update_dpp((int)0xFFFFFFFF, (int)x, 0x143, 0xF, 0xF, false); x = t < x ? t : x; // row_bcast:31
    return (unsigned)__builtin_amdgcn_readlane((int)x, 63);
}

// ---------------------------------------------------------------------------
// Kernel 2: JV LSAP. R2's bit-exact init (v=0, u=row-min, greedy argmin match:
// matched slack EXACTLY zero in fp, feasibility sign-exact) + R2's proven
// Phase C with a faster, value-exact argmin: DPP u32 min + ballot lowest-lane
// tie-break (== lowest column, lane-major ownership) + speculative row4col
// prefetch.
// ---------------------------------------------------------------------------
__global__ __launch_bounds__(256)
void hungarian_kernel(const float* __restrict__ cost,
                      float* __restrict__ outInds,
                      float* __restrict__ outMask)
{
    __shared__ float u[kNQ];
    __shared__ int   col4row[kNQ];
    __shared__ int   row4col[kNT];
    __shared__ int   colBest[kNT];
    __shared__ int   pathL[kNT];
    __shared__ int   rowArg[kNQ];

    const int b   = blockIdx.x;
    const int tid = threadIdx.x;
    const float* __restrict__ C = cost + (size_t)b * kNQ * kNT;

    // ---- Phase A: row minima + greedy matching (thread t == row t) ----
    {
        const float4* Crow = (const float4*)(C + (size_t)tid * kNT);
        float bm = kInf; int barg = 0;
        #pragma unroll 4
        for (int j4 = 0; j4 < kNT / 4; ++j4) {
            float4 cc = Crow[j4];
            const int jb = j4 * 4;
            if (cc.x < bm) { bm = cc.x; barg = jb + 0; }
            if (cc.y < bm) { bm = cc.y; barg = jb + 1; }
            if (cc.z < bm) { bm = cc.z; barg = jb + 2; }
            if (cc.w < bm) { bm = cc.w; barg = jb + 3; }
        }
        u[tid]      = bm;     // feasible: C - u - 0 >= 0 exactly; matched slack == 0 exactly
        rowArg[tid] = barg;
        col4row[tid] = -1;
    }
    row4col[tid] = -1;       row4col[tid + 256] = -1;
    colBest[tid] = 0x7fffffff; colBest[tid + 256] = 0x7fffffff;
    __syncthreads();
    atomicMin(&colBest[rowArg[tid]], tid);
    __syncthreads();
    {
        const int j = rowArg[tid];
        if (colBest[j] == tid) { col4row[tid] = j; row4col[j] = tid; }
    }
    __syncthreads();

    // ---- Phase C: augmenting searches, wave 0 only (wave-synchronous) ----
    if (tid < 64) {
        const int lane = tid;
        float vR[8];
        #pragma unroll
        for (int c = 0; c < 8; ++c) vR[c] = 0.f;

        for (int cur = 0; cur < kNQ; ++cur) {
            if (col4row[cur] >= 0) continue;   // uniform branch

            float spcR[8]; int pathR[8];
            #pragma unroll
            for (int c = 0; c < 8; ++c) { spcR[c] = kInf; pathR[c] = -1; }
            unsigned scMask = 0;

            int   i      = cur;
            float minVal = 0.f;
            int   sink   = -1;

            for (int guard = 0; guard < kNT + 2 && sink < 0; ++guard) {
                const float ui = u[i];
                const float4* rp = (const float4*)(C + (size_t)i * kNT + lane * 8);
                const float4 p0 = rp[0], p1 = rp[1];
                const float cc[8] = {p0.x, p0.y, p0.z, p0.w, p1.x, p1.y, p1.z, p1.w};
                #pragma unroll
                for (int c = 0; c < 8; ++c) {
                    if (!((scMask >> c) & 1u)) {
                        const float r = ((minVal + cc[c]) - ui) - vR[c];
                        if (r < spcR[c]) { spcR[c] = r; pathR[c] = i; }
                    }
                }

                // local argmin over 8 slots (u32 view, nonneg; strict < =>
                // lowest slot wins ties); swept slots masked to UINT_MAX
                unsigned sp[8];
                #pragma unroll
                for (int c = 0; c < 8; ++c)
                    sp[c] = ((scMask >> c) & 1u) ? 0xFFFFFFFFu
                                                 : __float_as_uint(spcR[c]);
                unsigned mA = sp[1] < sp[0] ? sp[1] : sp[0]; int aA = sp[1] < sp[0] ? 1 : 0;
                unsigned mB = sp[3] < sp[2] ? sp[3] : sp[2]; int aB = sp[3] < sp[2] ? 3 : 2;
                unsigned mC = sp[5] < sp[4] ? sp[5] : sp[4]; int aC = sp[5] < sp[4] ? 5 : 4;
                unsigned mD = sp[7] < sp[6] ? sp[7] : sp[6]; int aD = sp[7] < sp[6] ? 7 : 6;
                unsigned mAB = mB < mA ? mB : mA; int aAB = mB < mA ? aB : aA;
                unsigned mCD = mD < mC ? mD : mC; int aCD = mD < mC ? aD : aC;
                unsigned lvu = mCD < mAB ? mCD : mAB; int lc = mCD < mAB ? aCD : aAB;
                const int lix  = lane * 8 + lc;
                const int spec = row4col[lix];          // speculative owner prefetch

                const unsigned gmu = wave_min_u32(lvu); // hides the LDS read above
                const unsigned long long bal = __ballot(lvu == gmu);
                const int wl    = (int)__ffsll((unsigned long long)bal) - 1;
                const int jstar = __builtin_amdgcn_readlane(lix, wl);
                const int own   = __builtin_amdgcn_readlane(spec, wl);
                minVal = __uint_as_float(gmu);

                if (wl == lane) scMask |= 1u << (jstar & 7);
                if (own < 0) sink = jstar;
                else         i    = own;
            }

            // ---- dual updates (pre-augment matching, per swept column) ----
            if (lane == 0) u[cur] += minVal;
            #pragma unroll
            for (int c = 0; c < 8; ++c) {
                if ((scMask >> c) & 1u) {
                    const int j = lane * 8 + c;
                    const int r = row4col[j];
                    const float d = minVal - spcR[c];
                    if (r >= 0) u[r] += d;   // owners distinct (matching invariant)
                    vR[c] -= d;
                    pathL[j] = pathR[c];
                }
            }
            __threadfence_block();

            // ---- augment along alternating path (lane 0) ----
            if (lane == 0 && sink >= 0) {
                int j = sink;
                while (true) {
                    const int pi = pathL[j];
                    row4col[j] = pi;
                    const int nj = col4row[pi];
                    col4row[pi] = j;
                    if (pi == cur) break;
                    j = nj;
                }
            }
            __threadfence_block();
        }
    }
    __syncthreads();

    outInds[(size_t)b * kNQ + tid] = (float)col4row[tid];
    outMask[(size_t)b * kNQ + tid] = 1.0f;
}

extern "C" void kernel_launch(void* const* d_in, const int* in_sizes, int n_in,
                              void* d_out, int out_size, void* d_ws, size_t ws_size,
                              hipStream_t stream) {
    const float* trans = (const float*)d_in[0];
    const float* qpos  = (const float*)d_in[1];
    const float* rot   = (const float*)d_in[2];
    const float* pose  = (const float*)d_in[3];

    float* out  = (float*)d_out;
    float* cost = out;
    float* inds = out + (size_t)kB * kNQ * kNT;
    float* mask = inds + (size_t)kB * kNQ;

    dim3 g1(kB, kNQ / kQT);
    cost_kernel<<<g1, 256, 0, stream>>>(trans, qpos, rot, pose, cost);
    hungarian_kernel<<<kB, 256, 0, stream>>>(cost, inds, mask);
}